// Round 1
// baseline (944.117 us; speedup 1.0000x reference)
//
#include <hip/hip_runtime.h>

// SpectralWindowPreprocessor: out[b, c, j, h, w] = x[b, reflect(c + j - 3), h, w]
// B=4, C=31, WIN=7 (window size 3 -> 2*3+1), H=W=512, fp32, reflect padding
// (mask is all ones for reflect mode). Pure gather/broadcast copy -> memory bound.

#define NUM_C   31
#define WIN     7
#define HALF    3
#define HW      (512 * 512)
#define HW4     (HW / 4)        // 65536 float4 per plane
#define BATCH   4
#define PLANES  (BATCH * NUM_C * WIN)   // 868 output planes

__global__ __launch_bounds__(256)
void SpectralWindowPreprocessor_26912265076910_kernel(const float4* __restrict__ x,
                                                      float4* __restrict__ out)
{
    const int p     = blockIdx.x * 256 + threadIdx.x;  // 0 .. HW4-1 (coalesced)
    const int plane = blockIdx.y;                      // 0 .. PLANES-1

    // plane = ((b*NUM_C + c)*WIN + j)
    const int j = plane % WIN;
    const int c = (plane / WIN) % NUM_C;
    const int b = plane / (WIN * NUM_C);

    // reflect-pad channel index
    int t = c + j - HALF;
    if (t < 0)            t = -t - 1;
    else if (t >= NUM_C)  t = 2 * NUM_C - t - 1;

    out[(size_t)plane * HW4 + p] = x[(size_t)(b * NUM_C + t) * HW4 + p];
}

extern "C" void kernel_launch(void* const* d_in, const int* in_sizes, int n_in,
                              void* d_out, int out_size, void* d_ws, size_t ws_size,
                              hipStream_t stream) {
    const float4* x  = (const float4*)d_in[0];
    float4* out      = (float4*)d_out;

    dim3 grid(HW4 / 256, PLANES);   // (256, 868)
    dim3 block(256);
    SpectralWindowPreprocessor_26912265076910_kernel<<<grid, block, 0, stream>>>(x, out);
}